// Round 3
// 499.752 us; speedup vs baseline: 1.0109x; 1.0109x over previous
//
#include <hip/hip_runtime.h>

#define INV_SQRT2 0.70710678118654752440f

typedef __attribute__((ext_vector_type(8))) short bf16x8;   // 8 bf16 = 4 VGPRs (MFMA A/B frag)
typedef __attribute__((ext_vector_type(4))) float f32x4;    // MFMA C/D frag / native 16B vector
typedef __attribute__((ext_vector_type(8))) unsigned short u16x8;  // 16B bf16 load

__device__ __forceinline__ unsigned short f32_to_bf16_rne(float f) {
    unsigned int u = __builtin_bit_cast(unsigned int, f);
    u += 0x7FFFu + ((u >> 16) & 1u);       // round-to-nearest-even
    return (unsigned short)(u >> 16);
}
__device__ __forceinline__ float bf16_to_f32(unsigned short h) {
    return __builtin_bit_cast(float, ((unsigned int)h) << 16);
}

// ---------------------------------------------------------------------------
// Phase 0: convert [x | Wsrc | Wdst] fp32 -> bf16 into [xb | Wb].
// 8 elems/thread, 32B fp32 in, 16B bf16 out. ~38 MB traffic total -> ~6 us.
// ---------------------------------------------------------------------------
__global__ __launch_bounds__(256) void convert_k(
    const float* __restrict__ x,
    const float* __restrict__ Wsrc,
    const float* __restrict__ Wdst,
    unsigned short* __restrict__ xb,
    unsigned short* __restrict__ Wb,
    long long nx, int nw)   // nx = rows*64 (mult of 8), nw = 64*64
{
    long long t = (long long)blockIdx.x * 256 + threadIdx.x;
    long long total8 = (nx + 2LL * nw) >> 3;
    if (t >= total8) return;
    long long base = t << 3;

    const float* sp;
    unsigned short* dp;
    if (base < nx)            { sp = x    + base;            dp = xb + base; }
    else if (base < nx + nw)  { sp = Wsrc + (base - nx);      dp = Wb + (base - nx); }
    else                      { sp = Wdst + (base - nx - nw); dp = Wb + (base - nx); }

    float4 a = ((const float4*)sp)[0];
    float4 b = ((const float4*)sp)[1];
    uint4 o;
    o.x = (unsigned)f32_to_bf16_rne(a.x) | ((unsigned)f32_to_bf16_rne(a.y) << 16);
    o.y = (unsigned)f32_to_bf16_rne(a.z) | ((unsigned)f32_to_bf16_rne(a.w) << 16);
    o.z = (unsigned)f32_to_bf16_rne(b.x) | ((unsigned)f32_to_bf16_rne(b.y) << 16);
    o.w = (unsigned)f32_to_bf16_rne(b.z) | ((unsigned)f32_to_bf16_rne(b.w) << 16);
    *((uint4*)dp) = o;
}

// ---------------------------------------------------------------------------
// Phase 1: h[row][0:128] = (x[row] . W[n]) * INV_SQRT2 via bf16 MFMA.
// GEMM M=rows, N=128 (Wsrc|Wdst), K=64. One wave per 16-row tile; wave does
// all 8 col-tiles (A frags loaded once). Fragments load directly from
// row-major bf16: A[m=lane&15][k=quad*8+j], B[k=quad*8+j][n=lane&15]=W[n][k].
// ---------------------------------------------------------------------------
__global__ __launch_bounds__(256) void transform_mfma_k(
    const unsigned short* __restrict__ xb,   // (rows, 64) bf16
    const unsigned short* __restrict__ Wb,   // (128, 64) bf16  [Wsrc;Wdst]
    unsigned short* __restrict__ hb,         // (rows, 128) bf16
    int rows)
{
    int wave = (blockIdx.x * 256 + threadIdx.x) >> 6;
    int lane = threadIdx.x & 63;
    int row_tiles = (rows + 15) >> 4;
    if (wave >= row_tiles) return;

    int m    = lane & 15;
    int quad = lane >> 4;

    int arow_i = wave * 16 + m;
    if (arow_i >= rows) arow_i = rows - 1;          // clamp load (store is guarded)
    const bf16x8* arow = (const bf16x8*)(xb + (size_t)arow_i * 64);
    bf16x8 a0 = arow[quad];        // k = quad*8 + j,      k in [0,32)
    bf16x8 a1 = arow[4 + quad];    // k = 32 + quad*8 + j, k in [32,64)

    f32x4 acc[8];
#pragma unroll
    for (int ct = 0; ct < 8; ++ct) {
        int n = ct * 16 + m;
        const bf16x8* brow = (const bf16x8*)(Wb + (size_t)n * 64);
        bf16x8 b0 = brow[quad];
        bf16x8 b1 = brow[4 + quad];
        f32x4 c = {0.f, 0.f, 0.f, 0.f};
        c = __builtin_amdgcn_mfma_f32_16x16x32_bf16(a0, b0, c, 0, 0, 0);
        c = __builtin_amdgcn_mfma_f32_16x16x32_bf16(a1, b1, c, 0, 0, 0);
        acc[ct] = c;
    }

    // C/D layout: col = lane&15, row = quad*4 + r
#pragma unroll
    for (int ct = 0; ct < 8; ++ct) {
#pragma unroll
        for (int r = 0; r < 4; ++r) {
            int orow = wave * 16 + quad * 4 + r;
            if (orow < rows) {
                hb[(size_t)orow * 128 + ct * 16 + m] =
                    f32_to_bf16_rne(acc[ct][r] * INV_SQRT2);
            }
        }
    }
}

// ---------------------------------------------------------------------------
// Phase 2: out[b][e][:] = hs_row + hd_row (scale pre-folded).
// 8 lanes/edge, BOTH batches per thread:
//  - 4 independent 16B gathered loads in flight per thread (2x the MLP of the
//    old 16-lane/8B version), half the waves, half the redundant index loads.
//  - nontemporal 16B stores: the 409.6 MB output stream does not thrash
//    the 4 MB/XCD L2, so the 25.6 MB hb table stays cache-resident for the
//    random gathered reads.
// ---------------------------------------------------------------------------
__global__ __launch_bounds__(256) void gather_k(
    const unsigned short* __restrict__ hb,   // (B*N, 128) bf16
    const int* __restrict__ src,
    const int* __restrict__ dst,
    f32x4* __restrict__ out,
    int E, int N)
{
    int t = blockIdx.x * 256 + threadIdx.x;  // [0, E*8)
    if (t >= E * 8) return;
    int e = t >> 3;
    int c = t & 7;

    int s = src[e];
    int d = dst[e];

    const unsigned short* h0 = hb;                       // batch 0 rows
    const unsigned short* h1 = hb + (size_t)N * 128;     // batch 1 rows

    // issue all four gathered 16B loads back-to-back (independent)
    u16x8 us0 = *(const u16x8*)(h0 + (size_t)s * 128 + c * 8);
    u16x8 ud0 = *(const u16x8*)(h0 + (size_t)d * 128 + 64 + c * 8);
    u16x8 us1 = *(const u16x8*)(h1 + (size_t)s * 128 + c * 8);
    u16x8 ud1 = *(const u16x8*)(h1 + (size_t)d * 128 + 64 + c * 8);

    f32x4 o0a, o0b, o1a, o1b;
    o0a[0] = bf16_to_f32(us0[0]) + bf16_to_f32(ud0[0]);
    o0a[1] = bf16_to_f32(us0[1]) + bf16_to_f32(ud0[1]);
    o0a[2] = bf16_to_f32(us0[2]) + bf16_to_f32(ud0[2]);
    o0a[3] = bf16_to_f32(us0[3]) + bf16_to_f32(ud0[3]);
    o0b[0] = bf16_to_f32(us0[4]) + bf16_to_f32(ud0[4]);
    o0b[1] = bf16_to_f32(us0[5]) + bf16_to_f32(ud0[5]);
    o0b[2] = bf16_to_f32(us0[6]) + bf16_to_f32(ud0[6]);
    o0b[3] = bf16_to_f32(us0[7]) + bf16_to_f32(ud0[7]);
    o1a[0] = bf16_to_f32(us1[0]) + bf16_to_f32(ud1[0]);
    o1a[1] = bf16_to_f32(us1[1]) + bf16_to_f32(ud1[1]);
    o1a[2] = bf16_to_f32(us1[2]) + bf16_to_f32(ud1[2]);
    o1a[3] = bf16_to_f32(us1[3]) + bf16_to_f32(ud1[3]);
    o1b[0] = bf16_to_f32(us1[4]) + bf16_to_f32(ud1[4]);
    o1b[1] = bf16_to_f32(us1[5]) + bf16_to_f32(ud1[5]);
    o1b[2] = bf16_to_f32(us1[6]) + bf16_to_f32(ud1[6]);
    o1b[3] = bf16_to_f32(us1[7]) + bf16_to_f32(ud1[7]);

    size_t o0 = (size_t)e * 16 + (size_t)(c * 2);            // b = 0
    __builtin_nontemporal_store(o0a, &out[o0]);
    __builtin_nontemporal_store(o0b, &out[o0 + 1]);
    size_t o1 = ((size_t)E + (size_t)e) * 16 + (size_t)(c * 2);  // b = 1
    __builtin_nontemporal_store(o1a, &out[o1]);
    __builtin_nontemporal_store(o1b, &out[o1 + 1]);
}

// ---------------------------------------------------------------------------
// Fallback (ws too small): fused per-edge fp32 compute. Correct, slow.
// ---------------------------------------------------------------------------
__global__ __launch_bounds__(256) void fused_fallback_k(
    const float* __restrict__ x,
    const int* __restrict__ src,
    const int* __restrict__ dst,
    const float* __restrict__ Wsrc,
    const float* __restrict__ Wdst,
    float* __restrict__ out,
    int E, int N)
{
    int t = blockIdx.x * 256 + threadIdx.x;
    if (t >= E * 64) return;
    int o = t & 63;
    int e = t >> 6;
    int b = blockIdx.y;

    const float* xs = x + ((size_t)(b * N + src[e])) * 64;
    const float* xd = x + ((size_t)(b * N + dst[e])) * 64;
    const float* ws = Wsrc + o * 64;
    const float* wd = Wdst + o * 64;
    float acc = 0.0f;
#pragma unroll
    for (int k = 0; k < 64; ++k) {
        acc = fmaf(xs[k], ws[k], acc);
        acc = fmaf(xd[k], wd[k], acc);
    }
    out[((size_t)b * E + e) * 64 + o] = acc * INV_SQRT2;
}

extern "C" void kernel_launch(void* const* d_in, const int* in_sizes, int n_in,
                              void* d_out, int out_size, void* d_ws, size_t ws_size,
                              hipStream_t stream)
{
    const float* x    = (const float*)d_in[0];
    const int*   src  = (const int*)d_in[1];
    const int*   dst  = (const int*)d_in[2];
    const float* Wsrc = (const float*)d_in[3];
    const float* Wdst = (const float*)d_in[4];
    float* out = (float*)d_out;

    const int E = in_sizes[1];
    const long long xsz = in_sizes[0];
    const int B = (int)((long long)out_size / ((long long)E * 64));  // 2
    const int N = (int)(xsz / ((long long)B * 64));                  // 50000
    const int rows = B * N;                                          // 100000

    // ws layout: xb (rows*64 bf16) | Wb (128*64 bf16) | hb (rows*128 bf16)
    const size_t xb_elems = (size_t)rows * 64;
    const size_t wb_elems = 128 * 64;
    const size_t hb_elems = (size_t)rows * 128;
    const size_t need = (xb_elems + wb_elems + hb_elems) * sizeof(unsigned short);

    if (ws_size >= need && B == 2) {
        unsigned short* xb = (unsigned short*)d_ws;
        unsigned short* Wb = xb + xb_elems;
        unsigned short* hb = Wb + wb_elems;

        long long nx = (long long)rows * 64;
        int nw = 64 * 64;
        long long total8 = (nx + 2LL * nw) >> 3;
        int g0 = (int)((total8 + 255) / 256);
        convert_k<<<g0, 256, 0, stream>>>(x, Wsrc, Wdst, xb, Wb, nx, nw);

        int row_tiles = (rows + 15) >> 4;            // waves needed
        int g1 = (row_tiles + 3) / 4;                // 4 waves/block
        transform_mfma_k<<<g1, 256, 0, stream>>>(xb, Wb, hb, rows);

        int g2 = (E * 8 + 255) / 256;
        gather_k<<<g2, 256, 0, stream>>>(hb, src, dst, (f32x4*)out, E, N);
    } else {
        dim3 g((E * 64 + 255) / 256, B);
        fused_fallback_k<<<g, 256, 0, stream>>>(x, src, dst, Wsrc, Wdst, out, E, N);
    }
}